// Round 1
// baseline (518.932 us; speedup 1.0000x reference)
//
#include <hip/hip_runtime.h>
#include <math.h>

#define KF 8
#define LL 8
#define TT (1 << 18)
#define FF 2
#define HID 64
#define INF 16          // L*F = MLP input dim
// b1 / W2 per-cluster LDS stride (floats): 68%32=4 bank offset per cluster,
// keeps divergent-assign float4 reads at <=2-way conflict.
#define BS  68

// W1 is deliberately NOT staged in LDS: it is 32 KB total, L2-resident by
// construction (re-read by every block), and lanes sharing an 'assign'
// coalesce to identical addresses. Dropping it cuts LDS 38.4KB -> ~4.6KB,
// lifting the occupancy cap from 16 to 32 waves/CU (the gather loop is
// memory-latency-bound, so wave count is the lever).
__global__ __launch_bounds__(256, 8) void propnet_density_kernel(
    const float* __restrict__ positions,
    const float* __restrict__ centroids,
    const float* __restrict__ tables,
    const float* __restrict__ W1,
    const float* __restrict__ b1,
    const float* __restrict__ W2,
    const float* __restrict__ b2,
    float* __restrict__ out,
    int npts)
{
    __shared__ float sB1[KF * BS];    // 2176 B
    __shared__ float sW2[KF * BS];    // 2176 B
    __shared__ float sB2[KF];
    __shared__ float sC[KF * 3];

    const int tid = threadIdx.x;

    for (int idx = tid; idx < KF * HID; idx += blockDim.x) {
        int k = idx >> 6;
        int r = idx & 63;
        sB1[k * BS + r] = b1[idx];
        sW2[k * BS + r] = W2[idx];
    }
    if (tid < KF) sB2[tid] = b2[tid];
    if (tid < KF * 3) sC[tid] = centroids[tid];
    __syncthreads();

    const int gid = blockIdx.x * blockDim.x + tid;
    if (gid >= npts) return;

    const float px = positions[gid * 3 + 0];
    const float py = positions[gid * 3 + 1];
    const float pz = positions[gid * 3 + 2];

    // ---- cluster assignment: argmin_k ||p - c_k||^2 (first-min tie-break) ----
    int assign = 0;
    float best = 1e30f;
    #pragma unroll
    for (int k = 0; k < KF; ++k) {
        float dx = px - sC[k * 3 + 0];
        float dy = py - sC[k * 3 + 1];
        float dz = pz - sC[k * 3 + 2];
        float d2 = fmaf(dx, dx, fmaf(dy, dy, dz * dz));
        bool lt = d2 < best;
        assign = lt ? k : assign;
        best = lt ? d2 : best;
    }

    // ---- multiresolution hash encoding ----
    float enc[INF];
    const float2* __restrict__ tab =
        (const float2*)tables + (size_t)assign * (LL * (size_t)TT);

    #pragma unroll
    for (int l = 0; l < LL; ++l) {
        const float res = (float)(16 << l);
        const float sx = px * res, sy = py * res, sz = pz * res;
        const float fx = floorf(sx), fy = floorf(sy), fz = floorf(sz);
        const float wx = sx - fx, wy = sy - fy, wz = sz - fz;
        const unsigned ix = (unsigned)(int)fx;
        const unsigned iy = (unsigned)(int)fy;
        const unsigned iz = (unsigned)(int)fz;

        const float2* __restrict__ tl = tab + (size_t)l * TT;

        const unsigned hx0 = ix;                         // prime 1
        const unsigned hx1 = ix + 1u;
        const unsigned hy0 = iy * 2654435761u;
        const unsigned hy1 = (iy + 1u) * 2654435761u;
        const unsigned hz0 = iz * 805459861u;
        const unsigned hz1 = (iz + 1u) * 805459861u;
        const unsigned M = TT - 1;

        // 8 independent 8B gathers — keep them all in flight
        const float2 c000 = tl[(hx0 ^ hy0 ^ hz0) & M];
        const float2 c001 = tl[(hx0 ^ hy0 ^ hz1) & M];
        const float2 c010 = tl[(hx0 ^ hy1 ^ hz0) & M];
        const float2 c011 = tl[(hx0 ^ hy1 ^ hz1) & M];
        const float2 c100 = tl[(hx1 ^ hy0 ^ hz0) & M];
        const float2 c101 = tl[(hx1 ^ hy0 ^ hz1) & M];
        const float2 c110 = tl[(hx1 ^ hy1 ^ hz0) & M];
        const float2 c111 = tl[(hx1 ^ hy1 ^ hz1) & M];

        const float ux = 1.f - wx, uy = 1.f - wy, uz = 1.f - wz;
        const float w000 = ux * uy * uz, w001 = ux * uy * wz;
        const float w010 = ux * wy * uz, w011 = ux * wy * wz;
        const float w100 = wx * uy * uz, w101 = wx * uy * wz;
        const float w110 = wx * wy * uz, w111 = wx * wy * wz;

        enc[l * 2 + 0] = c000.x * w000 + c001.x * w001 + c010.x * w010 + c011.x * w011
                       + c100.x * w100 + c101.x * w101 + c110.x * w110 + c111.x * w111;
        enc[l * 2 + 1] = c000.y * w000 + c001.y * w001 + c010.y * w010 + c011.y * w011
                       + c100.y * w100 + c101.y * w101 + c110.y * w110 + c111.y * w111;
    }

    // ---- per-cluster MLP: out = b2 + sum_j relu(b1[j] + enc·W1[:,j]) * W2[j] ----
    // W1 read from global: L2-resident (32 KB), lanes with equal assign coalesce.
    const float4* __restrict__ w1k =
        (const float4*)(W1 + (size_t)assign * (INF * HID));
    const float4* __restrict__ b1k = (const float4*)(sB1 + assign * BS);
    const float4* __restrict__ w2k = (const float4*)(sW2 + assign * BS);

    float outv = sB2[assign];
    #pragma unroll
    for (int j4 = 0; j4 < HID / 4; ++j4) {
        float4 a = b1k[j4];
        #pragma unroll
        for (int i = 0; i < INF; ++i) {
            const float4 w = w1k[i * (HID / 4) + j4];   // global_load_dwordx4, L2-hit
            const float e = enc[i];
            a.x = fmaf(e, w.x, a.x);
            a.y = fmaf(e, w.y, a.y);
            a.z = fmaf(e, w.z, a.z);
            a.w = fmaf(e, w.w, a.w);
        }
        a.x = fmaxf(a.x, 0.f); a.y = fmaxf(a.y, 0.f);
        a.z = fmaxf(a.z, 0.f); a.w = fmaxf(a.w, 0.f);
        const float4 w2v = w2k[j4];
        outv = fmaf(a.x, w2v.x, outv);
        outv = fmaf(a.y, w2v.y, outv);
        outv = fmaf(a.z, w2v.z, outv);
        outv = fmaf(a.w, w2v.w, outv);
    }

    out[gid] = expf(outv);
}

extern "C" void kernel_launch(void* const* d_in, const int* in_sizes, int n_in,
                              void* d_out, int out_size, void* d_ws, size_t ws_size,
                              hipStream_t stream) {
    const float* positions = (const float*)d_in[0];
    const float* centroids = (const float*)d_in[1];
    const float* tables    = (const float*)d_in[2];
    const float* W1        = (const float*)d_in[3];
    const float* b1        = (const float*)d_in[4];
    const float* W2        = (const float*)d_in[5];
    const float* b2        = (const float*)d_in[6];
    float* out = (float*)d_out;

    const int npts = in_sizes[0] / 3;
    const int block = 256;
    const int grid = (npts + block - 1) / block;

    propnet_density_kernel<<<grid, block, 0, stream>>>(
        positions, centroids, tables, W1, b1, W2, b2, out, npts);
}

// Round 2
// 504.567 us; speedup vs baseline: 1.0285x; 1.0285x over previous
//
#include <hip/hip_runtime.h>
#include <math.h>

#define KF 8
#define LL 8
#define TT (1 << 18)
#define FF 2
#define HID 64
#define INF 16          // L*F = MLP input dim
// b1 / W2 per-cluster LDS stride (floats): 68%32=4 bank offset per cluster,
// keeps divergent-assign float4 reads at <=2-way conflict.
#define BS  68

// VGPR discipline is the whole game here (round-1 lesson):
//   - launch_bounds(256,8) clamped VGPR to 32 -> gathers serialized -> 373us.
//   - target band: VGPR <= 64 gives 8 waves/SIMD AND keeps 8 gathers in flight.
//   - gathers are addressed as u32 element indices off the SGPR-uniform
//     'tables' base (128 MB fits u32 byte offsets) -> 1 VGPR per address
//     (global_load_dwordx2 v, v_off, s[base:base+1]) instead of a 64-bit pair.
// W1 stays in global: 32 KB, L2-resident, lanes sharing 'assign' coalesce;
// keeping it out of LDS (4.6 KB total) removes the 4-blocks/CU LDS cap.
__global__ __launch_bounds__(256, 4) void propnet_density_kernel(
    const float* __restrict__ positions,
    const float* __restrict__ centroids,
    const float* __restrict__ tables,
    const float* __restrict__ W1,
    const float* __restrict__ b1,
    const float* __restrict__ W2,
    const float* __restrict__ b2,
    float* __restrict__ out,
    int npts)
{
    __shared__ float sB1[KF * BS];    // 2176 B
    __shared__ float sW2[KF * BS];    // 2176 B
    __shared__ float sB2[KF];
    __shared__ float sC[KF * 3];

    const int tid = threadIdx.x;

    for (int idx = tid; idx < KF * HID; idx += blockDim.x) {
        int k = idx >> 6;
        int r = idx & 63;
        sB1[k * BS + r] = b1[idx];
        sW2[k * BS + r] = W2[idx];
    }
    if (tid < KF) sB2[tid] = b2[tid];
    if (tid < KF * 3) sC[tid] = centroids[tid];
    __syncthreads();

    const int gid = blockIdx.x * blockDim.x + tid;
    if (gid >= npts) return;

    const float px = positions[gid * 3 + 0];
    const float py = positions[gid * 3 + 1];
    const float pz = positions[gid * 3 + 2];

    // ---- cluster assignment: argmin_k ||p - c_k||^2 (first-min tie-break) ----
    int assign = 0;
    float best = 1e30f;
    #pragma unroll
    for (int k = 0; k < KF; ++k) {
        float dx = px - sC[k * 3 + 0];
        float dy = py - sC[k * 3 + 1];
        float dz = pz - sC[k * 3 + 2];
        float d2 = fmaf(dx, dx, fmaf(dy, dy, dz * dz));
        bool lt = d2 < best;
        assign = lt ? k : assign;
        best = lt ? d2 : best;
    }

    // ---- multiresolution hash encoding ----
    float enc[INF];
    const float2* __restrict__ tab2 = (const float2*)tables;  // SGPR-uniform base
    const unsigned cbase = (unsigned)assign * (LL * TT);      // element index

    #pragma unroll
    for (int l = 0; l < LL; ++l) {
        const float res = (float)(16 << l);
        const float sx = px * res, sy = py * res, sz = pz * res;
        const float fx = floorf(sx), fy = floorf(sy), fz = floorf(sz);
        const float wx = sx - fx, wy = sy - fy, wz = sz - fz;
        const unsigned ix = (unsigned)(int)fx;
        const unsigned iy = (unsigned)(int)fy;
        const unsigned iz = (unsigned)(int)fz;

        const unsigned lb = cbase + (unsigned)l * TT;         // level base (elems)

        const unsigned hx0 = ix;                         // prime 1
        const unsigned hx1 = ix + 1u;
        const unsigned hy0 = iy * 2654435761u;
        const unsigned hy1 = (iy + 1u) * 2654435761u;
        const unsigned hz0 = iz * 805459861u;
        const unsigned hz1 = (iz + 1u) * 805459861u;
        const unsigned M = TT - 1;

        // 8 independent 8B gathers, u32 index off SGPR base — keep all in flight
        const float2 c000 = tab2[lb + ((hx0 ^ hy0 ^ hz0) & M)];
        const float2 c001 = tab2[lb + ((hx0 ^ hy0 ^ hz1) & M)];
        const float2 c010 = tab2[lb + ((hx0 ^ hy1 ^ hz0) & M)];
        const float2 c011 = tab2[lb + ((hx0 ^ hy1 ^ hz1) & M)];
        const float2 c100 = tab2[lb + ((hx1 ^ hy0 ^ hz0) & M)];
        const float2 c101 = tab2[lb + ((hx1 ^ hy0 ^ hz1) & M)];
        const float2 c110 = tab2[lb + ((hx1 ^ hy1 ^ hz0) & M)];
        const float2 c111 = tab2[lb + ((hx1 ^ hy1 ^ hz1) & M)];

        const float ux = 1.f - wx, uy = 1.f - wy, uz = 1.f - wz;
        const float w000 = ux * uy * uz, w001 = ux * uy * wz;
        const float w010 = ux * wy * uz, w011 = ux * wy * wz;
        const float w100 = wx * uy * uz, w101 = wx * uy * wz;
        const float w110 = wx * wy * uz, w111 = wx * wy * wz;

        enc[l * 2 + 0] = c000.x * w000 + c001.x * w001 + c010.x * w010 + c011.x * w011
                       + c100.x * w100 + c101.x * w101 + c110.x * w110 + c111.x * w111;
        enc[l * 2 + 1] = c000.y * w000 + c001.y * w001 + c010.y * w010 + c011.y * w011
                       + c100.y * w100 + c101.y * w101 + c110.y * w110 + c111.y * w111;
    }

    // ---- per-cluster MLP: out = b2 + sum_j relu(b1[j] + enc·W1[:,j]) * W2[j] ----
    // W1 read from global: L2-resident (32 KB), lanes with equal assign coalesce.
    const float4* __restrict__ w1k =
        (const float4*)(W1 + (size_t)assign * (INF * HID));
    const float4* __restrict__ b1k = (const float4*)(sB1 + assign * BS);
    const float4* __restrict__ w2k = (const float4*)(sW2 + assign * BS);

    float outv = sB2[assign];
    #pragma unroll
    for (int j4 = 0; j4 < HID / 4; ++j4) {
        float4 a = b1k[j4];
        #pragma unroll
        for (int i = 0; i < INF; ++i) {
            const float4 w = w1k[i * (HID / 4) + j4];   // global_load_dwordx4, L2-hit
            const float e = enc[i];
            a.x = fmaf(e, w.x, a.x);
            a.y = fmaf(e, w.y, a.y);
            a.z = fmaf(e, w.z, a.z);
            a.w = fmaf(e, w.w, a.w);
        }
        a.x = fmaxf(a.x, 0.f); a.y = fmaxf(a.y, 0.f);
        a.z = fmaxf(a.z, 0.f); a.w = fmaxf(a.w, 0.f);
        const float4 w2v = w2k[j4];
        outv = fmaf(a.x, w2v.x, outv);
        outv = fmaf(a.y, w2v.y, outv);
        outv = fmaf(a.z, w2v.z, outv);
        outv = fmaf(a.w, w2v.w, outv);
    }

    out[gid] = expf(outv);
}

extern "C" void kernel_launch(void* const* d_in, const int* in_sizes, int n_in,
                              void* d_out, int out_size, void* d_ws, size_t ws_size,
                              hipStream_t stream) {
    const float* positions = (const float*)d_in[0];
    const float* centroids = (const float*)d_in[1];
    const float* tables    = (const float*)d_in[2];
    const float* W1        = (const float*)d_in[3];
    const float* b1        = (const float*)d_in[4];
    const float* W2        = (const float*)d_in[5];
    const float* b2        = (const float*)d_in[6];
    float* out = (float*)d_out;

    const int npts = in_sizes[0] / 3;
    const int block = 256;
    const int grid = (npts + block - 1) / block;

    propnet_density_kernel<<<grid, block, 0, stream>>>(
        positions, centroids, tables, W1, b1, W2, b2, out, npts);
}

// Round 3
// 433.804 us; speedup vs baseline: 1.1962x; 1.1631x over previous
//
#include <hip/hip_runtime.h>
#include <math.h>

#define KF 8
#define LL 8
#define TT (1 << 18)
#define FF 2
#define HID 64
#define INF 16          // L*F = MLP input dim
// LDS strides (floats): W1 stride 1056 -> 8-bank-group step per cluster;
// b1/W2 stride 68 -> 4-bank offset per cluster (<=2-way conflict on float4).
#define W1S 1056
#define BS  68

// Round-3 structure: EXACT round-0 codegen shape (sW1 staged in LDS, 64-bit
// level pointers, no min-wave clamp -> compiler chose VGPR=56 and kept all 8
// gathers in flight), but TWO points per thread with the level loop fused:
//   issue A's 8 gathers -> issue B's 8 gathers -> consume A (vmcnt(8), B still
//   in flight under A's FMAs) -> consume B.
// Rationale: rounds 1-2 proved the compiler will NOT convert spare occupancy
// into loads-in-flight (it allocated 32/40 VGPR when allowed 128 and
// serialized). So we raise per-wave ILP directly: 16 loads in flight/wave,
// half the waves. Concurrency/CU ~ 16 waves x 16 vs round-0's 12 x 8-12.
__global__ __launch_bounds__(256) void propnet_density_kernel(
    const float* __restrict__ positions,
    const float* __restrict__ centroids,
    const float* __restrict__ tables,
    const float* __restrict__ W1,
    const float* __restrict__ b1,
    const float* __restrict__ W2,
    const float* __restrict__ b2,
    float* __restrict__ out,
    int npts)
{
    __shared__ float sW1[KF * W1S];   // 33792 B
    __shared__ float sB1[KF * BS];    //  2176 B
    __shared__ float sW2[KF * BS];    //  2176 B
    __shared__ float sB2[KF];
    __shared__ float sC[KF * 3];

    const int tid = threadIdx.x;

    // ---- cooperative weight staging (coalesced global reads) ----
    for (int idx = tid; idx < KF * INF * HID; idx += blockDim.x) {
        int k = idx >> 10;            // / (16*64)
        int r = idx & 1023;
        sW1[k * W1S + r] = W1[idx];
    }
    for (int idx = tid; idx < KF * HID; idx += blockDim.x) {
        int k = idx >> 6;
        int r = idx & 63;
        sB1[k * BS + r] = b1[idx];
        sW2[k * BS + r] = W2[idx];
    }
    if (tid < KF) sB2[tid] = b2[tid];
    if (tid < KF * 3) sC[tid] = centroids[tid];
    __syncthreads();

    // Two points per thread: block covers 512 consecutive points; thread t
    // takes base+t and base+t+256 (both globally coalesced).
    const int base = blockIdx.x * (2 * 256);
    const int gidA = base + tid;
    const int gidB = base + tid + 256;
    if (gidA >= npts) return;
    const bool hasB = (gidB < npts);
    const int gB = hasB ? gidB : gidA;   // harmless duplicate work on tail

    const float pxA = positions[gidA * 3 + 0];
    const float pyA = positions[gidA * 3 + 1];
    const float pzA = positions[gidA * 3 + 2];
    const float pxB = positions[gB * 3 + 0];
    const float pyB = positions[gB * 3 + 1];
    const float pzB = positions[gB * 3 + 2];

    // ---- cluster assignment for both points ----
    int assignA = 0, assignB = 0;
    float bestA = 1e30f, bestB = 1e30f;
    #pragma unroll
    for (int k = 0; k < KF; ++k) {
        const float cx = sC[k * 3 + 0], cy = sC[k * 3 + 1], cz = sC[k * 3 + 2];
        float dxA = pxA - cx, dyA = pyA - cy, dzA = pzA - cz;
        float d2A = fmaf(dxA, dxA, fmaf(dyA, dyA, dzA * dzA));
        bool ltA = d2A < bestA;
        assignA = ltA ? k : assignA;
        bestA = ltA ? d2A : bestA;
        float dxB = pxB - cx, dyB = pyB - cy, dzB = pzB - cz;
        float d2B = fmaf(dxB, dxB, fmaf(dyB, dyB, dzB * dzB));
        bool ltB = d2B < bestB;
        assignB = ltB ? k : assignB;
        bestB = ltB ? d2B : bestB;
    }

    // ---- multiresolution hash encoding, both points fused per level ----
    float encA[INF], encB[INF];
    const float2* __restrict__ tabA =
        (const float2*)tables + (size_t)assignA * (LL * (size_t)TT);
    const float2* __restrict__ tabB =
        (const float2*)tables + (size_t)assignB * (LL * (size_t)TT);

    #pragma unroll
    for (int l = 0; l < LL; ++l) {
        const float res = (float)(16 << l);
        const unsigned M = TT - 1;

        // --- point A: hashes + issue 8 gathers ---
        const float sxA = pxA * res, syA = pyA * res, szA = pzA * res;
        const float fxA = floorf(sxA), fyA = floorf(syA), fzA = floorf(szA);
        const float wxA = sxA - fxA, wyA = syA - fyA, wzA = szA - fzA;
        const unsigned ixA = (unsigned)(int)fxA;
        const unsigned iyA = (unsigned)(int)fyA;
        const unsigned izA = (unsigned)(int)fzA;
        const float2* __restrict__ tlA = tabA + (size_t)l * TT;
        const unsigned ax0 = ixA, ax1 = ixA + 1u;
        const unsigned ay0 = iyA * 2654435761u, ay1 = (iyA + 1u) * 2654435761u;
        const unsigned az0 = izA * 805459861u,  az1 = (izA + 1u) * 805459861u;

        const float2 a000 = tlA[(ax0 ^ ay0 ^ az0) & M];
        const float2 a001 = tlA[(ax0 ^ ay0 ^ az1) & M];
        const float2 a010 = tlA[(ax0 ^ ay1 ^ az0) & M];
        const float2 a011 = tlA[(ax0 ^ ay1 ^ az1) & M];
        const float2 a100 = tlA[(ax1 ^ ay0 ^ az0) & M];
        const float2 a101 = tlA[(ax1 ^ ay0 ^ az1) & M];
        const float2 a110 = tlA[(ax1 ^ ay1 ^ az0) & M];
        const float2 a111 = tlA[(ax1 ^ ay1 ^ az1) & M];

        // --- point B: hashes + issue 8 gathers (stay in flight over A's FMAs) ---
        const float sxB = pxB * res, syB = pyB * res, szB = pzB * res;
        const float fxB = floorf(sxB), fyB = floorf(syB), fzB = floorf(szB);
        const float wxB = sxB - fxB, wyB = syB - fyB, wzB = szB - fzB;
        const unsigned ixB = (unsigned)(int)fxB;
        const unsigned iyB = (unsigned)(int)fyB;
        const unsigned izB = (unsigned)(int)fzB;
        const float2* __restrict__ tlB = tabB + (size_t)l * TT;
        const unsigned bx0 = ixB, bx1 = ixB + 1u;
        const unsigned by0 = iyB * 2654435761u, by1 = (iyB + 1u) * 2654435761u;
        const unsigned bz0 = izB * 805459861u,  bz1 = (izB + 1u) * 805459861u;

        const float2 b000 = tlB[(bx0 ^ by0 ^ bz0) & M];
        const float2 b001 = tlB[(bx0 ^ by0 ^ bz1) & M];
        const float2 b010 = tlB[(bx0 ^ by1 ^ bz0) & M];
        const float2 b011 = tlB[(bx0 ^ by1 ^ bz1) & M];
        const float2 b100 = tlB[(bx1 ^ by0 ^ bz0) & M];
        const float2 b101 = tlB[(bx1 ^ by0 ^ bz1) & M];
        const float2 b110 = tlB[(bx1 ^ by1 ^ bz0) & M];
        const float2 b111 = tlB[(bx1 ^ by1 ^ bz1) & M];

        // --- consume A (waits vmcnt(8); B's loads still outstanding) ---
        {
            const float ux = 1.f - wxA, uy = 1.f - wyA, uz = 1.f - wzA;
            const float w000 = ux * uy * uz, w001 = ux * uy * wzA;
            const float w010 = ux * wyA * uz, w011 = ux * wyA * wzA;
            const float w100 = wxA * uy * uz, w101 = wxA * uy * wzA;
            const float w110 = wxA * wyA * uz, w111 = wxA * wyA * wzA;
            encA[l * 2 + 0] = a000.x * w000 + a001.x * w001 + a010.x * w010 + a011.x * w011
                            + a100.x * w100 + a101.x * w101 + a110.x * w110 + a111.x * w111;
            encA[l * 2 + 1] = a000.y * w000 + a001.y * w001 + a010.y * w010 + a011.y * w011
                            + a100.y * w100 + a101.y * w101 + a110.y * w110 + a111.y * w111;
        }
        // --- consume B ---
        {
            const float ux = 1.f - wxB, uy = 1.f - wyB, uz = 1.f - wzB;
            const float w000 = ux * uy * uz, w001 = ux * uy * wzB;
            const float w010 = ux * wyB * uz, w011 = ux * wyB * wzB;
            const float w100 = wxB * uy * uz, w101 = wxB * uy * wzB;
            const float w110 = wxB * wyB * uz, w111 = wxB * wyB * wzB;
            encB[l * 2 + 0] = b000.x * w000 + b001.x * w001 + b010.x * w010 + b011.x * w011
                            + b100.x * w100 + b101.x * w101 + b110.x * w110 + b111.x * w111;
            encB[l * 2 + 1] = b000.y * w000 + b001.y * w001 + b010.y * w010 + b011.y * w011
                            + b100.y * w100 + b101.y * w101 + b110.y * w110 + b111.y * w111;
        }
    }

    // ---- per-cluster MLP for both points (W1 from LDS) ----
    const float4* __restrict__ w1kA = (const float4*)(sW1 + assignA * W1S);
    const float4* __restrict__ b1kA = (const float4*)(sB1 + assignA * BS);
    const float4* __restrict__ w2kA = (const float4*)(sW2 + assignA * BS);
    const float4* __restrict__ w1kB = (const float4*)(sW1 + assignB * W1S);
    const float4* __restrict__ b1kB = (const float4*)(sB1 + assignB * BS);
    const float4* __restrict__ w2kB = (const float4*)(sW2 + assignB * BS);

    float outvA = sB2[assignA];
    float outvB = sB2[assignB];
    #pragma unroll
    for (int j4 = 0; j4 < HID / 4; ++j4) {
        float4 aA = b1kA[j4];
        float4 aB = b1kB[j4];
        #pragma unroll
        for (int i = 0; i < INF; ++i) {
            const float4 wA = w1kA[i * (HID / 4) + j4];   // ds_read_b128
            const float4 wB = w1kB[i * (HID / 4) + j4];
            const float eA = encA[i];
            const float eB = encB[i];
            aA.x = fmaf(eA, wA.x, aA.x);
            aA.y = fmaf(eA, wA.y, aA.y);
            aA.z = fmaf(eA, wA.z, aA.z);
            aA.w = fmaf(eA, wA.w, aA.w);
            aB.x = fmaf(eB, wB.x, aB.x);
            aB.y = fmaf(eB, wB.y, aB.y);
            aB.z = fmaf(eB, wB.z, aB.z);
            aB.w = fmaf(eB, wB.w, aB.w);
        }
        aA.x = fmaxf(aA.x, 0.f); aA.y = fmaxf(aA.y, 0.f);
        aA.z = fmaxf(aA.z, 0.f); aA.w = fmaxf(aA.w, 0.f);
        aB.x = fmaxf(aB.x, 0.f); aB.y = fmaxf(aB.y, 0.f);
        aB.z = fmaxf(aB.z, 0.f); aB.w = fmaxf(aB.w, 0.f);
        const float4 w2A = w2kA[j4];
        const float4 w2B = w2kB[j4];
        outvA = fmaf(aA.x, w2A.x, outvA);
        outvA = fmaf(aA.y, w2A.y, outvA);
        outvA = fmaf(aA.z, w2A.z, outvA);
        outvA = fmaf(aA.w, w2A.w, outvA);
        outvB = fmaf(aB.x, w2B.x, outvB);
        outvB = fmaf(aB.y, w2B.y, outvB);
        outvB = fmaf(aB.z, w2B.z, outvB);
        outvB = fmaf(aB.w, w2B.w, outvB);
    }

    out[gidA] = expf(outvA);
    if (hasB) out[gidB] = expf(outvB);
}

extern "C" void kernel_launch(void* const* d_in, const int* in_sizes, int n_in,
                              void* d_out, int out_size, void* d_ws, size_t ws_size,
                              hipStream_t stream) {
    const float* positions = (const float*)d_in[0];
    const float* centroids = (const float*)d_in[1];
    const float* tables    = (const float*)d_in[2];
    const float* W1        = (const float*)d_in[3];
    const float* b1        = (const float*)d_in[4];
    const float* W2        = (const float*)d_in[5];
    const float* b2        = (const float*)d_in[6];
    float* out = (float*)d_out;

    const int npts = in_sizes[0] / 3;
    const int block = 256;
    const int ptsPerBlock = 2 * block;
    const int grid = (npts + ptsPerBlock - 1) / ptsPerBlock;

    propnet_density_kernel<<<grid, block, 0, stream>>>(
        positions, centroids, tables, W1, b1, W2, b2, out, npts);
}

// Round 4
// 433.690 us; speedup vs baseline: 1.1966x; 1.0003x over previous
//
#include <hip/hip_runtime.h>
#include <math.h>

#define KF 8
#define LL 8
#define TT (1 << 18)
#define FF 2
#define HID 64
#define INF 16          // L*F = MLP input dim
// LDS strides (floats), chosen so the 8 per-lane 'assign' values map to
// distinct/2-way bank groups for float4 reads:
//   W1: stride 1056 -> (1056/4)%32 = 8 bank-group step per cluster
#define W1S 1056
#define BS  68          // b1 / W2 per-cluster stride (68%32=4 offset; 2-way max)

// Round-4: EXACT round-0 per-thread structure (sW1 in LDS, 64-bit level
// pointers, 8 gathers in flight, VGPR ~56), but 512-thread blocks.
// LDS is per-BLOCK (38.4 KB): 256-thread blocks capped occupancy at
// 4 blocks x 4 waves = 16 waves/CU; 512-thread blocks give 4 blocks x 8
// waves = 32 waves/CU (HW max) with identical per-thread codegen.
// Rounds 1-3 lesson: the compiler will not trade occupancy for ILP or
// vice versa profitably — so raise wave count while freezing the known-good
// 8-loads-in-flight schedule. NO min-waves clamp (r1/r2 showed it
// collapses VGPR to 32/40 and serializes the gathers).
__global__ __launch_bounds__(512) void propnet_density_kernel(
    const float* __restrict__ positions,
    const float* __restrict__ centroids,
    const float* __restrict__ tables,
    const float* __restrict__ W1,
    const float* __restrict__ b1,
    const float* __restrict__ W2,
    const float* __restrict__ b2,
    float* __restrict__ out,
    int npts)
{
    __shared__ float sW1[KF * W1S];   // 33792 B
    __shared__ float sB1[KF * BS];    //  2176 B
    __shared__ float sW2[KF * BS];    //  2176 B
    __shared__ float sB2[KF];
    __shared__ float sC[KF * 3];

    const int tid = threadIdx.x;

    // ---- cooperative weight staging (coalesced global reads) ----
    for (int idx = tid; idx < KF * INF * HID; idx += blockDim.x) {
        int k = idx >> 10;            // / (16*64)
        int r = idx & 1023;
        sW1[k * W1S + r] = W1[idx];
    }
    for (int idx = tid; idx < KF * HID; idx += blockDim.x) {
        int k = idx >> 6;
        int r = idx & 63;
        sB1[k * BS + r] = b1[idx];
        sW2[k * BS + r] = W2[idx];
    }
    if (tid < KF) sB2[tid] = b2[tid];
    if (tid < KF * 3) sC[tid] = centroids[tid];
    __syncthreads();

    const int gid = blockIdx.x * blockDim.x + tid;
    if (gid >= npts) return;

    const float px = positions[gid * 3 + 0];
    const float py = positions[gid * 3 + 1];
    const float pz = positions[gid * 3 + 2];

    // ---- cluster assignment: argmin_k ||p - c_k||^2 (first-min tie-break) ----
    int assign = 0;
    float best = 1e30f;
    #pragma unroll
    for (int k = 0; k < KF; ++k) {
        float dx = px - sC[k * 3 + 0];
        float dy = py - sC[k * 3 + 1];
        float dz = pz - sC[k * 3 + 2];
        float d2 = fmaf(dx, dx, fmaf(dy, dy, dz * dz));
        bool lt = d2 < best;
        assign = lt ? k : assign;
        best = lt ? d2 : best;
    }

    // ---- multiresolution hash encoding ----
    float enc[INF];
    const float2* __restrict__ tab =
        (const float2*)tables + (size_t)assign * (LL * (size_t)TT);

    #pragma unroll
    for (int l = 0; l < LL; ++l) {
        const float res = (float)(16 << l);
        const float sx = px * res, sy = py * res, sz = pz * res;
        const float fx = floorf(sx), fy = floorf(sy), fz = floorf(sz);
        const float wx = sx - fx, wy = sy - fy, wz = sz - fz;
        const unsigned ix = (unsigned)(int)fx;
        const unsigned iy = (unsigned)(int)fy;
        const unsigned iz = (unsigned)(int)fz;

        const float2* __restrict__ tl = tab + (size_t)l * TT;

        const unsigned hx0 = ix;                         // prime 1
        const unsigned hx1 = ix + 1u;
        const unsigned hy0 = iy * 2654435761u;
        const unsigned hy1 = (iy + 1u) * 2654435761u;
        const unsigned hz0 = iz * 805459861u;
        const unsigned hz1 = (iz + 1u) * 805459861u;
        const unsigned M = TT - 1;

        // 8 independent 8B gathers — keep them all in flight
        const float2 c000 = tl[(hx0 ^ hy0 ^ hz0) & M];
        const float2 c001 = tl[(hx0 ^ hy0 ^ hz1) & M];
        const float2 c010 = tl[(hx0 ^ hy1 ^ hz0) & M];
        const float2 c011 = tl[(hx0 ^ hy1 ^ hz1) & M];
        const float2 c100 = tl[(hx1 ^ hy0 ^ hz0) & M];
        const float2 c101 = tl[(hx1 ^ hy0 ^ hz1) & M];
        const float2 c110 = tl[(hx1 ^ hy1 ^ hz0) & M];
        const float2 c111 = tl[(hx1 ^ hy1 ^ hz1) & M];

        const float ux = 1.f - wx, uy = 1.f - wy, uz = 1.f - wz;
        const float w000 = ux * uy * uz, w001 = ux * uy * wz;
        const float w010 = ux * wy * uz, w011 = ux * wy * wz;
        const float w100 = wx * uy * uz, w101 = wx * uy * wz;
        const float w110 = wx * wy * uz, w111 = wx * wy * wz;

        enc[l * 2 + 0] = c000.x * w000 + c001.x * w001 + c010.x * w010 + c011.x * w011
                       + c100.x * w100 + c101.x * w101 + c110.x * w110 + c111.x * w111;
        enc[l * 2 + 1] = c000.y * w000 + c001.y * w001 + c010.y * w010 + c011.y * w011
                       + c100.y * w100 + c101.y * w101 + c110.y * w110 + c111.y * w111;
    }

    // ---- per-cluster MLP: out = b2 + sum_j relu(b1[j] + enc·W1[:,j]) * W2[j] ----
    const float4* __restrict__ w1k = (const float4*)(sW1 + assign * W1S);
    const float4* __restrict__ b1k = (const float4*)(sB1 + assign * BS);
    const float4* __restrict__ w2k = (const float4*)(sW2 + assign * BS);

    float outv = sB2[assign];
    #pragma unroll
    for (int j4 = 0; j4 < HID / 4; ++j4) {
        float4 a = b1k[j4];
        #pragma unroll
        for (int i = 0; i < INF; ++i) {
            const float4 w = w1k[i * (HID / 4) + j4];   // ds_read_b128
            const float e = enc[i];
            a.x = fmaf(e, w.x, a.x);
            a.y = fmaf(e, w.y, a.y);
            a.z = fmaf(e, w.z, a.z);
            a.w = fmaf(e, w.w, a.w);
        }
        a.x = fmaxf(a.x, 0.f); a.y = fmaxf(a.y, 0.f);
        a.z = fmaxf(a.z, 0.f); a.w = fmaxf(a.w, 0.f);
        const float4 w2v = w2k[j4];
        outv = fmaf(a.x, w2v.x, outv);
        outv = fmaf(a.y, w2v.y, outv);
        outv = fmaf(a.z, w2v.z, outv);
        outv = fmaf(a.w, w2v.w, outv);
    }

    out[gid] = expf(outv);
}

extern "C" void kernel_launch(void* const* d_in, const int* in_sizes, int n_in,
                              void* d_out, int out_size, void* d_ws, size_t ws_size,
                              hipStream_t stream) {
    const float* positions = (const float*)d_in[0];
    const float* centroids = (const float*)d_in[1];
    const float* tables    = (const float*)d_in[2];
    const float* W1        = (const float*)d_in[3];
    const float* b1        = (const float*)d_in[4];
    const float* W2        = (const float*)d_in[5];
    const float* b2        = (const float*)d_in[6];
    float* out = (float*)d_out;

    const int npts = in_sizes[0] / 3;
    const int block = 512;   // 8 waves/block; LDS (38.4KB) caps 4 blocks/CU
                             // -> 32 waves/CU vs 16 with 256-thread blocks
    const int grid = (npts + block - 1) / block;

    propnet_density_kernel<<<grid, block, 0, stream>>>(
        positions, centroids, tables, W1, b1, W2, b2, out, npts);
}

// Round 5
// 409.862 us; speedup vs baseline: 1.2661x; 1.0581x over previous
//
#include <hip/hip_runtime.h>
#include <hip/hip_fp16.h>
#include <math.h>

#define KF 8
#define LL 8
#define TT (1 << 18)
#define FF 2
#define HID 64
#define INF 16          // L*F = MLP input dim
// LDS strides (floats), chosen so the 8 per-lane 'assign' values map to
// distinct/2-way bank groups for float4 reads:
//   W1: stride 1056 -> (1056/4)%32 = 8 bank-group step per cluster
#define W1S 1056
#define BS  68          // b1 / W2 per-cluster stride (68%32=4 offset; 2-way max)

#define NENT (KF * LL * TT)   // 16,777,216 table entries

// ---------------------------------------------------------------------------
// Round-5: rounds 0/3/4 proved the kernel is pinned at a ~3 TB/s memory-side
// fill wall (concurrency varied 2x, duration flat, FETCH/dur saturated).
// Only reducing miss traffic helps. Repack tables fp32->half2 (128->64 MB)
// into the workspace each launch (~30us streaming), then gather 4B half2:
//   - hot random footprint halves -> better L2/L3 retention
//   - 32B sector covers 8 entries instead of 4
// Accuracy: table ~N(0,1e-2), fp16 rel err ~5e-4 -> output absmax ~1e-4.
// Weights / positions / MLP stay fp32.
// ---------------------------------------------------------------------------

__global__ __launch_bounds__(256) void repack_tables_fp16(
    const float2* __restrict__ tables, __half2* __restrict__ wsTab, int nent)
{
    int i = blockIdx.x * blockDim.x + threadIdx.x;
    const int stride = gridDim.x * blockDim.x;
    for (; i < nent; i += stride) {
        const float2 v = tables[i];
        wsTab[i] = __floats2half2_rn(v.x, v.y);
    }
}

// Main kernel: EXACT round-0 structure (sW1 in LDS, 64-bit level pointers,
// 8 gathers in flight, no min-wave clamp), gathers are half2.
__global__ __launch_bounds__(256) void propnet_density_kernel_h(
    const float* __restrict__ positions,
    const float* __restrict__ centroids,
    const __half2* __restrict__ tables,
    const float* __restrict__ W1,
    const float* __restrict__ b1,
    const float* __restrict__ W2,
    const float* __restrict__ b2,
    float* __restrict__ out,
    int npts)
{
    __shared__ float sW1[KF * W1S];   // 33792 B
    __shared__ float sB1[KF * BS];    //  2176 B
    __shared__ float sW2[KF * BS];    //  2176 B
    __shared__ float sB2[KF];
    __shared__ float sC[KF * 3];

    const int tid = threadIdx.x;

    for (int idx = tid; idx < KF * INF * HID; idx += blockDim.x) {
        int k = idx >> 10;            // / (16*64)
        int r = idx & 1023;
        sW1[k * W1S + r] = W1[idx];
    }
    for (int idx = tid; idx < KF * HID; idx += blockDim.x) {
        int k = idx >> 6;
        int r = idx & 63;
        sB1[k * BS + r] = b1[idx];
        sW2[k * BS + r] = W2[idx];
    }
    if (tid < KF) sB2[tid] = b2[tid];
    if (tid < KF * 3) sC[tid] = centroids[tid];
    __syncthreads();

    const int gid = blockIdx.x * blockDim.x + tid;
    if (gid >= npts) return;

    const float px = positions[gid * 3 + 0];
    const float py = positions[gid * 3 + 1];
    const float pz = positions[gid * 3 + 2];

    // ---- cluster assignment: argmin_k ||p - c_k||^2 (first-min tie-break) ----
    int assign = 0;
    float best = 1e30f;
    #pragma unroll
    for (int k = 0; k < KF; ++k) {
        float dx = px - sC[k * 3 + 0];
        float dy = py - sC[k * 3 + 1];
        float dz = pz - sC[k * 3 + 2];
        float d2 = fmaf(dx, dx, fmaf(dy, dy, dz * dz));
        bool lt = d2 < best;
        assign = lt ? k : assign;
        best = lt ? d2 : best;
    }

    // ---- multiresolution hash encoding (half2 gathers) ----
    float enc[INF];
    const __half2* __restrict__ tab =
        tables + (size_t)assign * (LL * (size_t)TT);

    #pragma unroll
    for (int l = 0; l < LL; ++l) {
        const float res = (float)(16 << l);
        const float sx = px * res, sy = py * res, sz = pz * res;
        const float fx = floorf(sx), fy = floorf(sy), fz = floorf(sz);
        const float wx = sx - fx, wy = sy - fy, wz = sz - fz;
        const unsigned ix = (unsigned)(int)fx;
        const unsigned iy = (unsigned)(int)fy;
        const unsigned iz = (unsigned)(int)fz;

        const __half2* __restrict__ tl = tab + (size_t)l * TT;

        const unsigned hx0 = ix;                         // prime 1
        const unsigned hx1 = ix + 1u;
        const unsigned hy0 = iy * 2654435761u;
        const unsigned hy1 = (iy + 1u) * 2654435761u;
        const unsigned hz0 = iz * 805459861u;
        const unsigned hz1 = (iz + 1u) * 805459861u;
        const unsigned M = TT - 1;

        // 8 independent 4B gathers — keep them all in flight
        const __half2 c000 = tl[(hx0 ^ hy0 ^ hz0) & M];
        const __half2 c001 = tl[(hx0 ^ hy0 ^ hz1) & M];
        const __half2 c010 = tl[(hx0 ^ hy1 ^ hz0) & M];
        const __half2 c011 = tl[(hx0 ^ hy1 ^ hz1) & M];
        const __half2 c100 = tl[(hx1 ^ hy0 ^ hz0) & M];
        const __half2 c101 = tl[(hx1 ^ hy0 ^ hz1) & M];
        const __half2 c110 = tl[(hx1 ^ hy1 ^ hz0) & M];
        const __half2 c111 = tl[(hx1 ^ hy1 ^ hz1) & M];

        const float ux = 1.f - wx, uy = 1.f - wy, uz = 1.f - wz;
        const float w000 = ux * uy * uz, w001 = ux * uy * wz;
        const float w010 = ux * wy * uz, w011 = ux * wy * wz;
        const float w100 = wx * uy * uz, w101 = wx * uy * wz;
        const float w110 = wx * wy * uz, w111 = wx * wy * wz;

        enc[l * 2 + 0] = __low2float(c000) * w000 + __low2float(c001) * w001
                       + __low2float(c010) * w010 + __low2float(c011) * w011
                       + __low2float(c100) * w100 + __low2float(c101) * w101
                       + __low2float(c110) * w110 + __low2float(c111) * w111;
        enc[l * 2 + 1] = __high2float(c000) * w000 + __high2float(c001) * w001
                       + __high2float(c010) * w010 + __high2float(c011) * w011
                       + __high2float(c100) * w100 + __high2float(c101) * w101
                       + __high2float(c110) * w110 + __high2float(c111) * w111;
    }

    // ---- per-cluster MLP: out = b2 + sum_j relu(b1[j] + enc·W1[:,j]) * W2[j] ----
    const float4* __restrict__ w1k = (const float4*)(sW1 + assign * W1S);
    const float4* __restrict__ b1k = (const float4*)(sB1 + assign * BS);
    const float4* __restrict__ w2k = (const float4*)(sW2 + assign * BS);

    float outv = sB2[assign];
    #pragma unroll
    for (int j4 = 0; j4 < HID / 4; ++j4) {
        float4 a = b1k[j4];
        #pragma unroll
        for (int i = 0; i < INF; ++i) {
            const float4 w = w1k[i * (HID / 4) + j4];   // ds_read_b128
            const float e = enc[i];
            a.x = fmaf(e, w.x, a.x);
            a.y = fmaf(e, w.y, a.y);
            a.z = fmaf(e, w.z, a.z);
            a.w = fmaf(e, w.w, a.w);
        }
        a.x = fmaxf(a.x, 0.f); a.y = fmaxf(a.y, 0.f);
        a.z = fmaxf(a.z, 0.f); a.w = fmaxf(a.w, 0.f);
        const float4 w2v = w2k[j4];
        outv = fmaf(a.x, w2v.x, outv);
        outv = fmaf(a.y, w2v.y, outv);
        outv = fmaf(a.z, w2v.z, outv);
        outv = fmaf(a.w, w2v.w, outv);
    }

    out[gid] = expf(outv);
}

// Fallback (workspace too small): exact round-0 fp32 kernel.
__global__ __launch_bounds__(256) void propnet_density_kernel_f(
    const float* __restrict__ positions,
    const float* __restrict__ centroids,
    const float* __restrict__ tables,
    const float* __restrict__ W1,
    const float* __restrict__ b1,
    const float* __restrict__ W2,
    const float* __restrict__ b2,
    float* __restrict__ out,
    int npts)
{
    __shared__ float sW1[KF * W1S];
    __shared__ float sB1[KF * BS];
    __shared__ float sW2[KF * BS];
    __shared__ float sB2[KF];
    __shared__ float sC[KF * 3];

    const int tid = threadIdx.x;

    for (int idx = tid; idx < KF * INF * HID; idx += blockDim.x) {
        int k = idx >> 10;
        int r = idx & 1023;
        sW1[k * W1S + r] = W1[idx];
    }
    for (int idx = tid; idx < KF * HID; idx += blockDim.x) {
        int k = idx >> 6;
        int r = idx & 63;
        sB1[k * BS + r] = b1[idx];
        sW2[k * BS + r] = W2[idx];
    }
    if (tid < KF) sB2[tid] = b2[tid];
    if (tid < KF * 3) sC[tid] = centroids[tid];
    __syncthreads();

    const int gid = blockIdx.x * blockDim.x + tid;
    if (gid >= npts) return;

    const float px = positions[gid * 3 + 0];
    const float py = positions[gid * 3 + 1];
    const float pz = positions[gid * 3 + 2];

    int assign = 0;
    float best = 1e30f;
    #pragma unroll
    for (int k = 0; k < KF; ++k) {
        float dx = px - sC[k * 3 + 0];
        float dy = py - sC[k * 3 + 1];
        float dz = pz - sC[k * 3 + 2];
        float d2 = fmaf(dx, dx, fmaf(dy, dy, dz * dz));
        bool lt = d2 < best;
        assign = lt ? k : assign;
        best = lt ? d2 : best;
    }

    float enc[INF];
    const float2* __restrict__ tab =
        (const float2*)tables + (size_t)assign * (LL * (size_t)TT);

    #pragma unroll
    for (int l = 0; l < LL; ++l) {
        const float res = (float)(16 << l);
        const float sx = px * res, sy = py * res, sz = pz * res;
        const float fx = floorf(sx), fy = floorf(sy), fz = floorf(sz);
        const float wx = sx - fx, wy = sy - fy, wz = sz - fz;
        const unsigned ix = (unsigned)(int)fx;
        const unsigned iy = (unsigned)(int)fy;
        const unsigned iz = (unsigned)(int)fz;

        const float2* __restrict__ tl = tab + (size_t)l * TT;

        const unsigned hx0 = ix;
        const unsigned hx1 = ix + 1u;
        const unsigned hy0 = iy * 2654435761u;
        const unsigned hy1 = (iy + 1u) * 2654435761u;
        const unsigned hz0 = iz * 805459861u;
        const unsigned hz1 = (iz + 1u) * 805459861u;
        const unsigned M = TT - 1;

        const float2 c000 = tl[(hx0 ^ hy0 ^ hz0) & M];
        const float2 c001 = tl[(hx0 ^ hy0 ^ hz1) & M];
        const float2 c010 = tl[(hx0 ^ hy1 ^ hz0) & M];
        const float2 c011 = tl[(hx0 ^ hy1 ^ hz1) & M];
        const float2 c100 = tl[(hx1 ^ hy0 ^ hz0) & M];
        const float2 c101 = tl[(hx1 ^ hy0 ^ hz1) & M];
        const float2 c110 = tl[(hx1 ^ hy1 ^ hz0) & M];
        const float2 c111 = tl[(hx1 ^ hy1 ^ hz1) & M];

        const float ux = 1.f - wx, uy = 1.f - wy, uz = 1.f - wz;
        const float w000 = ux * uy * uz, w001 = ux * uy * wz;
        const float w010 = ux * wy * uz, w011 = ux * wy * wz;
        const float w100 = wx * uy * uz, w101 = wx * uy * wz;
        const float w110 = wx * wy * uz, w111 = wx * wy * wz;

        enc[l * 2 + 0] = c000.x * w000 + c001.x * w001 + c010.x * w010 + c011.x * w011
                       + c100.x * w100 + c101.x * w101 + c110.x * w110 + c111.x * w111;
        enc[l * 2 + 1] = c000.y * w000 + c001.y * w001 + c010.y * w010 + c011.y * w011
                       + c100.y * w100 + c101.y * w101 + c110.y * w110 + c111.y * w111;
    }

    const float4* __restrict__ w1k = (const float4*)(sW1 + assign * W1S);
    const float4* __restrict__ b1k = (const float4*)(sB1 + assign * BS);
    const float4* __restrict__ w2k = (const float4*)(sW2 + assign * BS);

    float outv = sB2[assign];
    #pragma unroll
    for (int j4 = 0; j4 < HID / 4; ++j4) {
        float4 a = b1k[j4];
        #pragma unroll
        for (int i = 0; i < INF; ++i) {
            const float4 w = w1k[i * (HID / 4) + j4];
            const float e = enc[i];
            a.x = fmaf(e, w.x, a.x);
            a.y = fmaf(e, w.y, a.y);
            a.z = fmaf(e, w.z, a.z);
            a.w = fmaf(e, w.w, a.w);
        }
        a.x = fmaxf(a.x, 0.f); a.y = fmaxf(a.y, 0.f);
        a.z = fmaxf(a.z, 0.f); a.w = fmaxf(a.w, 0.f);
        const float4 w2v = w2k[j4];
        outv = fmaf(a.x, w2v.x, outv);
        outv = fmaf(a.y, w2v.y, outv);
        outv = fmaf(a.z, w2v.z, outv);
        outv = fmaf(a.w, w2v.w, outv);
    }

    out[gid] = expf(outv);
}

extern "C" void kernel_launch(void* const* d_in, const int* in_sizes, int n_in,
                              void* d_out, int out_size, void* d_ws, size_t ws_size,
                              hipStream_t stream) {
    const float* positions = (const float*)d_in[0];
    const float* centroids = (const float*)d_in[1];
    const float* tables    = (const float*)d_in[2];
    const float* W1        = (const float*)d_in[3];
    const float* b1        = (const float*)d_in[4];
    const float* W2        = (const float*)d_in[5];
    const float* b2        = (const float*)d_in[6];
    float* out = (float*)d_out;

    const int npts = in_sizes[0] / 3;
    const int block = 256;
    const int grid = (npts + block - 1) / block;

    const size_t needed = (size_t)NENT * sizeof(__half2);   // 64 MiB
    if (ws_size >= needed && d_ws != nullptr) {
        // repack tables fp32 -> half2 (re-run every launch: inputs may be
        // re-poisoned between iterations)
        repack_tables_fp16<<<2048, 256, 0, stream>>>(
            (const float2*)tables, (__half2*)d_ws, NENT);
        propnet_density_kernel_h<<<grid, block, 0, stream>>>(
            positions, centroids, (const __half2*)d_ws, W1, b1, W2, b2, out, npts);
    } else {
        propnet_density_kernel_f<<<grid, block, 0, stream>>>(
            positions, centroids, tables, W1, b1, W2, b2, out, npts);
    }
}